// Round 1
// baseline (191.880 us; speedup 1.0000x reference)
//
#include <hip/hip_runtime.h>
#include <hip/hip_bf16.h>
#include <math.h>

// Problem constants
#define B_  4
#define T_  2048
#define D_  512
#define H_  4
#define DK_ 16
#define NC_ 260           // 64 q + 64 k + 64 v + 64 g + 4 a
#define ROWS_ (B_*T_)     // 8192

// ---------------------------------------------------------------------------
// Pack Wq|Wk|Wv|Wg|Wa into Wcat (512 x 260), row-major.
// ---------------------------------------------------------------------------
__global__ void pack_w(const float* __restrict__ Wq, const float* __restrict__ Wk,
                       const float* __restrict__ Wv, const float* __restrict__ Wg,
                       const float* __restrict__ Wa, float* __restrict__ Wcat) {
    int idx = blockIdx.x * 256 + threadIdx.x;
    if (idx >= D_ * NC_) return;
    int r = idx / NC_;
    int c = idx - r * NC_;
    float v;
    if (c < 64)       v = Wq[r * 64 + c];
    else if (c < 128) v = Wk[r * 64 + (c - 64)];
    else if (c < 192) v = Wv[r * 64 + (c - 128)];
    else if (c < 256) v = Wg[r * 64 + (c - 192)];
    else              v = Wa[r * 4  + (c - 256)];
    Wcat[idx] = v;
}

// ---------------------------------------------------------------------------
// Tiled fp32 GEMM: C(M,N) = A(M,K) @ B(K,N), row-major.
// 64x64 block tile, 256 threads, 4x4 micro-tile, K-tile 16 in LDS.
// M % 64 == 0, K % 16 == 0, N % 4 == 0 assumed (true for both uses).
// ---------------------------------------------------------------------------
#define TM 64
#define TN 64
#define TK 16

__global__ __launch_bounds__(256) void gemm_tiled(const float* __restrict__ A,
                                                  const float* __restrict__ Bm,
                                                  float* __restrict__ C,
                                                  int M, int N, int K) {
    __shared__ float As[TK][TM];   // [k][m]
    __shared__ float Bs[TK][TN];   // [k][n]
    int tid = threadIdx.x;
    int block_row = blockIdx.y * TM;
    int block_col = blockIdx.x * TN;
    int ty = tid >> 4;   // 0..15 -> rows ty*4..ty*4+3
    int tx = tid & 15;   // 0..15 -> cols tx*4..tx*4+3

    float acc[4][4] = {{0.f}};

    for (int k0 = 0; k0 < K; k0 += TK) {
        // A tile: 64 rows x 16 k, one float4 per thread (coalesced)
        {
            int r  = tid >> 2;          // 0..63
            int c4 = (tid & 3) * 4;     // 0,4,8,12
            const float4 av = *(const float4*)&A[(size_t)(block_row + r) * K + k0 + c4];
            As[c4 + 0][r] = av.x;
            As[c4 + 1][r] = av.y;
            As[c4 + 2][r] = av.z;
            As[c4 + 3][r] = av.w;
        }
        // B tile: 16 k x 64 cols, scalar with N bounds (N=260 edge)
        #pragma unroll
        for (int i = 0; i < 4; i++) {
            int idx = tid + i * 256;
            int r = idx >> 6;           // 0..15
            int c = idx & 63;
            int col = block_col + c;
            Bs[r][c] = (col < N) ? Bm[(size_t)(k0 + r) * N + col] : 0.0f;
        }
        __syncthreads();

        #pragma unroll
        for (int kk = 0; kk < TK; kk++) {
            float4 av = *(const float4*)&As[kk][ty * 4];
            float4 bv = *(const float4*)&Bs[kk][tx * 4];
            float a0[4] = {av.x, av.y, av.z, av.w};
            float b0[4] = {bv.x, bv.y, bv.z, bv.w};
            #pragma unroll
            for (int i = 0; i < 4; i++)
                #pragma unroll
                for (int j = 0; j < 4; j++)
                    acc[i][j] = fmaf(a0[i], b0[j], acc[i][j]);
        }
        __syncthreads();
    }

    // store 4x4 as float4 rows (N % 4 == 0 so per-float4 bound check is exact)
    #pragma unroll
    for (int i = 0; i < 4; i++) {
        int r = block_row + ty * 4 + i;
        int col = block_col + tx * 4;
        if (col < N) {
            float4 ov = make_float4(acc[i][0], acc[i][1], acc[i][2], acc[i][3]);
            *(float4*)&C[(size_t)r * N + col] = ov;
        }
    }
}

// ---------------------------------------------------------------------------
// Scan kernel: one block per (b,h). 256 threads x 8 steps each = 2048.
// Phase 1: cumsum of a  (scalar block scan)
// Phase 2: online-softmax prefix scan, state (m, den, num[16])
// Output: Y[row, h*16+j] = (num/den) * sigmoid(g_pre + bg)
// ---------------------------------------------------------------------------
#define SPT 8   // steps per thread

__global__ __launch_bounds__(256) void scan_kernel(const float* __restrict__ C1,
                                                   const float* __restrict__ ba,
                                                   const float* __restrict__ bg,
                                                   float* __restrict__ Y) {
    __shared__ float sm[256];
    __shared__ float sd[256];
    __shared__ float sn[256 * 17];   // stride 17 to kill bank conflicts
    __shared__ float sbuf[256];

    int b = blockIdx.x >> 2;
    int h = blockIdx.x & 3;
    int tid = threadIdx.x;
    int t0 = tid * SPT;
    size_t rowbase = (size_t)b * T_;

    const float ba_h = ba[h];
    const int qc = h * 16, kc = 64 + h * 16, vc = 128 + h * 16, gc = 192 + h * 16;

    float lg[SPT];
    float a_loc[SPT];

    // per-step: bid and a
    for (int i = 0; i < SPT; i++) {
        const float* row = C1 + (rowbase + t0 + i) * NC_;
        float bid = 0.f;
        #pragma unroll
        for (int j = 0; j < 16; j++) bid = fmaf(row[qc + j], row[kc + j], bid);
        bid *= 0.25f;                       // / sqrt(16)
        float z = row[256 + h] + ba_h;
        float sp = fmaxf(z, 0.f) + log1pf(expf(-fabsf(z)));   // softplus
        a_loc[i] = -sp;
        lg[i] = bid;
    }

    // ---- Phase 1: block scan of a-sums -> cumA ----
    float asum = 0.f;
    for (int i = 0; i < SPT; i++) asum += a_loc[i];
    float val = asum;
    sbuf[tid] = val;
    __syncthreads();
    for (int off = 1; off < 256; off <<= 1) {
        float other = (tid >= off) ? sbuf[tid - off] : 0.0f;
        __syncthreads();
        val += other;
        sbuf[tid] = val;
        __syncthreads();
    }
    float run = val - asum;   // exclusive prefix of thread totals
    for (int i = 0; i < SPT; i++) {
        run += a_loc[i];      // inclusive cumA at step t0+i
        lg[i] -= run;         // lg = bid - cumA
    }

    // ---- Phase 2: thread-local online-softmax summary ----
    float m = -INFINITY, d = 0.f, n[16];
    #pragma unroll
    for (int j = 0; j < 16; j++) n[j] = 0.f;
    for (int i = 0; i < SPT; i++) {
        const float* vp = C1 + (rowbase + t0 + i) * NC_ + vc;
        float mn = fmaxf(m, lg[i]);
        float al = expf(m - mn);          // exp(-inf)=0 on first iter
        float be = expf(lg[i] - mn);
        d = d * al + be;
        #pragma unroll
        for (int j = 0; j < 16; j++) n[j] = n[j] * al + be * vp[j];
        m = mn;
    }

    // ---- block scan of (m,d,n[16]) states (Hillis-Steele, left-combine) ----
    sm[tid] = m; sd[tid] = d;
    #pragma unroll
    for (int j = 0; j < 16; j++) sn[tid * 17 + j] = n[j];
    __syncthreads();
    for (int off = 1; off < 256; off <<= 1) {
        float Lm = 0.f, Ld = 0.f, Ln[16];
        bool has = (tid >= off);
        if (has) {
            Lm = sm[tid - off]; Ld = sd[tid - off];
            #pragma unroll
            for (int j = 0; j < 16; j++) Ln[j] = sn[(tid - off) * 17 + j];
        }
        __syncthreads();
        if (has) {
            float mn = fmaxf(Lm, m);
            float al = expf(Lm - mn);
            float be = expf(m - mn);
            d = Ld * al + d * be;
            #pragma unroll
            for (int j = 0; j < 16; j++) n[j] = Ln[j] * al + n[j] * be;
            m = mn;
            sm[tid] = m; sd[tid] = d;
            #pragma unroll
            for (int j = 0; j < 16; j++) sn[tid * 17 + j] = n[j];
        }
        __syncthreads();
    }

    // exclusive prefix = inclusive state of thread tid-1
    float pm = -INFINITY, pd = 0.f, pn[16];
    #pragma unroll
    for (int j = 0; j < 16; j++) pn[j] = 0.f;
    if (tid > 0) {
        pm = sm[tid - 1]; pd = sd[tid - 1];
        #pragma unroll
        for (int j = 0; j < 16; j++) pn[j] = sn[(tid - 1) * 17 + j];
    }

    // ---- re-walk: inclusive result per step, apply gate, write Y ----
    for (int i = 0; i < SPT; i++) {
        size_t row = rowbase + t0 + i;
        const float* vp = C1 + row * NC_ + vc;
        const float* gp = C1 + row * NC_ + gc;
        float mn = fmaxf(pm, lg[i]);
        float al = expf(pm - mn);
        float be = expf(lg[i] - mn);
        pd = pd * al + be;
        #pragma unroll
        for (int j = 0; j < 16; j++) pn[j] = pn[j] * al + be * vp[j];
        pm = mn;
        float invd = 1.0f / pd;
        #pragma unroll
        for (int j = 0; j < 16; j++) {
            float g = gp[j] + bg[h * 16 + j];
            float gate = 1.0f / (1.0f + expf(-g));
            Y[row * 64 + h * 16 + j] = pn[j] * invd * gate;
        }
    }
}

// ---------------------------------------------------------------------------
extern "C" void kernel_launch(void* const* d_in, const int* in_sizes, int n_in,
                              void* d_out, int out_size, void* d_ws, size_t ws_size,
                              hipStream_t stream) {
    const float* x  = (const float*)d_in[0];
    const float* Wq = (const float*)d_in[1];
    const float* Wk = (const float*)d_in[2];
    const float* Wv = (const float*)d_in[3];
    const float* Wa = (const float*)d_in[4];
    const float* ba = (const float*)d_in[5];
    const float* Wg = (const float*)d_in[6];
    const float* bg = (const float*)d_in[7];
    const float* Wo = (const float*)d_in[8];
    float* out = (float*)d_out;

    float* ws   = (float*)d_ws;
    float* Wcat = ws;                              // 512*260   = 133120
    float* C1   = Wcat + (size_t)D_ * NC_;         // 8192*260  = 2129920
    float* Y    = C1 + (size_t)ROWS_ * NC_;        // 8192*64   = 524288

    // 1. pack weights
    pack_w<<<(D_ * NC_ + 255) / 256, 256, 0, stream>>>(Wq, Wk, Wv, Wg, Wa, Wcat);

    // 2. projections: C1 = x @ Wcat   (8192 x 260)
    dim3 g1((NC_ + TN - 1) / TN, ROWS_ / TM);
    gemm_tiled<<<g1, 256, 0, stream>>>(x, Wcat, C1, ROWS_, NC_, D_);

    // 3. tropical-SSM prefix scan + gate -> Y (8192 x 64)
    scan_kernel<<<B_ * H_, 256, 0, stream>>>(C1, ba, bg, Y);

    // 4. out = Y @ Wo   (8192 x 512)
    dim3 g2(D_ / TN, ROWS_ / TM);
    gemm_tiled<<<g2, 256, 0, stream>>>(Y, Wo, out, ROWS_, D_, 64);
}

// Round 2
// 153.821 us; speedup vs baseline: 1.2474x; 1.2474x over previous
//
#include <hip/hip_runtime.h>
#include <math.h>

// Problem constants
#define B_    4
#define T_    2048
#define D_    512
#define H_    4
#define ROWS_ 8192
#define NCH_  16      // chunks per (b,h)
#define CHSZ_ 128     // timesteps per chunk

typedef unsigned short ushort_t;
typedef unsigned int   uint_t;
typedef __attribute__((ext_vector_type(8))) __bf16     bfx8;
typedef __attribute__((ext_vector_type(8))) unsigned short u16x8;
typedef __attribute__((ext_vector_type(4))) float      fx4;

__device__ __forceinline__ ushort_t f2bf(float f) {
    union { float f; uint_t u; } v; v.f = f;
    uint_t r = (v.u + 0x7FFFu + ((v.u >> 16) & 1u)) >> 16;
    return (ushort_t)r;
}
__device__ __forceinline__ float bf2f(ushort_t u) {
    union { uint_t u; float f; } v; v.u = ((uint_t)u) << 16; return v.f;
}

// ---------------------------------------------------------------------------
// a-projection (fp32, exact): Aarr[row][h] = -softplus(x[row]·Wa[:,h] + ba[h])
// One wave per row-group; x read once.
// ---------------------------------------------------------------------------
__global__ __launch_bounds__(256) void a_proj(const float* __restrict__ x,
                                              const float* __restrict__ Wa,
                                              const float* __restrict__ ba,
                                              float* __restrict__ Aarr) {
    int wave = threadIdx.x >> 6, lane = threadIdx.x & 63;
    float wa[8][4];
    #pragma unroll
    for (int j = 0; j < 8; j++) {
        float4 t = *(const float4*)&Wa[(lane * 8 + j) * 4];
        wa[j][0] = t.x; wa[j][1] = t.y; wa[j][2] = t.z; wa[j][3] = t.w;
    }
    for (int r = 0; r < 16; r++) {
        int row = blockIdx.x * 64 + wave * 16 + r;
        const float* xp = x + (size_t)row * D_ + lane * 8;
        float4 v0 = *(const float4*)xp;
        float4 v1 = *(const float4*)(xp + 4);
        float xv[8] = {v0.x, v0.y, v0.z, v0.w, v1.x, v1.y, v1.z, v1.w};
        float a0 = 0.f, a1 = 0.f, a2 = 0.f, a3 = 0.f;
        #pragma unroll
        for (int j = 0; j < 8; j++) {
            a0 = fmaf(xv[j], wa[j][0], a0);
            a1 = fmaf(xv[j], wa[j][1], a1);
            a2 = fmaf(xv[j], wa[j][2], a2);
            a3 = fmaf(xv[j], wa[j][3], a3);
        }
        #pragma unroll
        for (int off = 32; off; off >>= 1) {
            a0 += __shfl_xor(a0, off);
            a1 += __shfl_xor(a1, off);
            a2 += __shfl_xor(a2, off);
            a3 += __shfl_xor(a3, off);
        }
        if (lane == 0) {
            float zz[4] = {a0 + ba[0], a1 + ba[1], a2 + ba[2], a3 + ba[3]};
            #pragma unroll
            for (int h = 0; h < 4; h++) {
                float z = zz[h];
                float sp = fmaxf(z, 0.f) + log1pf(expf(-fabsf(z)));
                Aarr[(size_t)row * 4 + h] = -sp;
            }
        }
    }
}

// ---------------------------------------------------------------------------
// Pack weights to bf16, transposed ([n][k] so MFMA B-frags are contiguous).
// WcatT: 256 x 512  (q|k|v|g).   WoT: 512 x 64.
// ---------------------------------------------------------------------------
__global__ __launch_bounds__(256) void pack_w_bf(const float* __restrict__ Wq,
                                                 const float* __restrict__ Wk,
                                                 const float* __restrict__ Wv,
                                                 const float* __restrict__ Wg,
                                                 const float* __restrict__ Wo,
                                                 ushort_t* __restrict__ WcatT,
                                                 ushort_t* __restrict__ WoT) {
    int idx = blockIdx.x * 256 + threadIdx.x;
    if (idx < 256 * 512) {
        int n = idx >> 9, d = idx & 511;
        const float* W = (n < 64) ? Wq : (n < 128) ? Wk : (n < 192) ? Wv : Wg;
        int c = n & 63;
        WcatT[idx] = f2bf(W[(size_t)d * 64 + c]);
    } else {
        int r = idx - 256 * 512;          // 0..32767
        int n = r >> 6, k = r & 63;
        WoT[r] = f2bf(Wo[(size_t)k * 512 + n]);
    }
}

// ---------------------------------------------------------------------------
// bf16 MFMA GEMM: C(MxN) = A(MxK) @ BT(NxK)^T.   BM=64 BN=128 BK=64.
// 256 threads = 4 waves (2x2), each wave 32x64 (2x4 tiles of 16x16x32).
// A is float (converted on the fly) or bf16(ushort); C is float or bf16.
// LDS rows padded to 72 bf16 -> worst 2-way bank aliasing (free).
// ---------------------------------------------------------------------------
template <typename AT, typename CT>
__global__ __launch_bounds__(256) void gemm_bt(const AT* __restrict__ A,
                                               const ushort_t* __restrict__ BT,
                                               CT* __restrict__ C,
                                               int M, int N, int K) {
    __shared__ ushort_t As[64 * 72];
    __shared__ ushort_t Bs[128 * 72];
    const int tid = threadIdx.x;
    const int wave = tid >> 6, lane = tid & 63;
    const int m0 = blockIdx.y * 64, n0 = blockIdx.x * 128;
    const int wr = wave >> 1, wc = wave & 1;

    fx4 acc[2][4];
    #pragma unroll
    for (int i = 0; i < 2; i++)
        #pragma unroll
        for (int j = 0; j < 4; j++) acc[i][j] = (fx4)0.f;

    const int sr = tid >> 3;          // 0..31 staging row
    const int sc = (tid & 7) * 8;     // staging k-offset (8 bf16 = 16 B)

    for (int k0 = 0; k0 < K; k0 += 64) {
        // stage A (64 x 64)
        #pragma unroll
        for (int s = 0; s < 2; s++) {
            int r = s * 32 + sr;
            const AT* gp = A + (size_t)(m0 + r) * K + k0 + sc;
            u16x8 u;
            if constexpr (sizeof(AT) == 4) {
                float4 f0 = *(const float4*)gp;
                float4 f1 = *(const float4*)(gp + 4);
                u[0] = f2bf(f0.x); u[1] = f2bf(f0.y); u[2] = f2bf(f0.z); u[3] = f2bf(f0.w);
                u[4] = f2bf(f1.x); u[5] = f2bf(f1.y); u[6] = f2bf(f1.z); u[7] = f2bf(f1.w);
            } else {
                u = *(const u16x8*)gp;
            }
            *(u16x8*)&As[r * 72 + sc] = u;
        }
        // stage B (128 x 64)
        #pragma unroll
        for (int s = 0; s < 4; s++) {
            int r = s * 32 + sr;
            *(u16x8*)&Bs[r * 72 + sc] = *(const u16x8*)(BT + (size_t)(n0 + r) * K + k0 + sc);
        }
        __syncthreads();

        const int fr = lane & 15, quad = lane >> 4;
        #pragma unroll
        for (int ks = 0; ks < 64; ks += 32) {
            bfx8 af[2], bfr[4];
            #pragma unroll
            for (int mi = 0; mi < 2; mi++)
                af[mi] = *(const bfx8*)&As[(wr * 32 + mi * 16 + fr) * 72 + ks + quad * 8];
            #pragma unroll
            for (int ni = 0; ni < 4; ni++)
                bfr[ni] = *(const bfx8*)&Bs[(wc * 64 + ni * 16 + fr) * 72 + ks + quad * 8];
            #pragma unroll
            for (int mi = 0; mi < 2; mi++)
                #pragma unroll
                for (int ni = 0; ni < 4; ni++)
                    acc[mi][ni] = __builtin_amdgcn_mfma_f32_16x16x32_bf16(af[mi], bfr[ni], acc[mi][ni], 0, 0, 0);
        }
        __syncthreads();
    }

    const int fr = lane & 15, quad = lane >> 4;
    #pragma unroll
    for (int mi = 0; mi < 2; mi++)
        #pragma unroll
        for (int ni = 0; ni < 4; ni++)
            #pragma unroll
            for (int r = 0; r < 4; r++) {
                int rr = m0 + wr * 32 + mi * 16 + quad * 4 + r;
                int cc = n0 + wc * 64 + ni * 16 + fr;
                if constexpr (sizeof(CT) == 4) C[(size_t)rr * N + cc] = acc[mi][ni][r];
                else                           C[(size_t)rr * N + cc] = f2bf(acc[mi][ni][r]);
            }
}

// ---------------------------------------------------------------------------
// Scan phase A: per (b,h,chunk) block (128 threads, 1 step/thread):
// chunk-local inclusive scan of a (-> cumA_loc) and of softmax state
// (m,d,n[16]) over lg_loc = bid - cumA_loc. Writes per-element states and a
// per-chunk summary. Combine is commutative in (m,d,n) representation.
// ---------------------------------------------------------------------------
__global__ __launch_bounds__(128) void scan_phaseA(const ushort_t* __restrict__ C1,
                                                   const float* __restrict__ Aarr,
                                                   float* __restrict__ stateWS,
                                                   float* __restrict__ chunkSum) {
    const int blk = blockIdx.x;
    const int bh = blk >> 4, chunk = blk & 15;
    const int b = bh >> 2, h = bh & 3;
    const int tid = threadIdx.x;
    const int t = chunk * CHSZ_ + tid;
    const size_t row = (size_t)b * T_ + t;
    const int lane = tid & 63, w = tid >> 6;

    const ushort_t* rp = C1 + row * 256;
    u16x8 q0 = *(const u16x8*)(rp + h * 16);
    u16x8 q1 = *(const u16x8*)(rp + h * 16 + 8);
    u16x8 k0 = *(const u16x8*)(rp + 64 + h * 16);
    u16x8 k1 = *(const u16x8*)(rp + 64 + h * 16 + 8);
    float bid = 0.f;
    #pragma unroll
    for (int j = 0; j < 8; j++) {
        bid = fmaf(bf2f(q0[j]), bf2f(k0[j]), bid);
        bid = fmaf(bf2f(q1[j]), bf2f(k1[j]), bid);
    }
    bid *= 0.25f;
    float a = Aarr[row * 4 + h];

    // inclusive scan of a over the 128-thread chunk
    float ca = a;
    #pragma unroll
    for (int off = 1; off < 64; off <<= 1) {
        float up = __shfl_up(ca, off);
        if (lane >= off) ca += up;
    }
    __shared__ float s_a0;
    __shared__ float s_state[18];
    if (w == 0 && lane == 63) s_a0 = ca;
    __syncthreads();
    if (w == 1) ca += s_a0;

    float lg = bid - ca;

    // element state
    float m = lg, d = 1.f;
    float n[16];
    u16x8 v0 = *(const u16x8*)(rp + 128 + h * 16);
    u16x8 v1 = *(const u16x8*)(rp + 128 + h * 16 + 8);
    #pragma unroll
    for (int j = 0; j < 8; j++) { n[j] = bf2f(v0[j]); n[8 + j] = bf2f(v1[j]); }

    // wave-level inclusive state scan (combine is commutative)
    #pragma unroll
    for (int off = 1; off < 64; off <<= 1) {
        float Lm = __shfl_up(m, off);
        float Ld = __shfl_up(d, off);
        float Ln[16];
        #pragma unroll
        for (int j = 0; j < 16; j++) Ln[j] = __shfl_up(n[j], off);
        if (lane >= off) {
            float mn = fmaxf(Lm, m);
            float al = __expf(Lm - mn), be = __expf(m - mn);
            d = Ld * al + d * be;
            #pragma unroll
            for (int j = 0; j < 16; j++) n[j] = Ln[j] * al + n[j] * be;
            m = mn;
        }
    }
    // cross-wave: wave 0 total is prefix for wave 1
    if (w == 0 && lane == 63) {
        s_state[0] = m; s_state[1] = d;
        #pragma unroll
        for (int j = 0; j < 16; j++) s_state[2 + j] = n[j];
    }
    __syncthreads();
    if (w == 1) {
        float Lm = s_state[0], Ld = s_state[1];
        float mn = fmaxf(Lm, m);
        float al = __expf(Lm - mn), be = __expf(m - mn);
        d = Ld * al + d * be;
        #pragma unroll
        for (int j = 0; j < 16; j++) n[j] = s_state[2 + j] * al + n[j] * be;
        m = mn;
    }

    // write per-element inclusive local state (18 planes, coalesced)
    size_t eidx = (size_t)bh * T_ + t;
    stateWS[eidx] = m;
    stateWS[32768 + eidx] = d;
    #pragma unroll
    for (int j = 0; j < 16; j++) stateWS[(size_t)(2 + j) * 32768 + eidx] = n[j];

    if (tid == CHSZ_ - 1) {
        float* cs = chunkSum + (size_t)(bh * 16 + chunk) * 20;
        cs[0] = m; cs[1] = d;
        #pragma unroll
        for (int j = 0; j < 16; j++) cs[2 + j] = n[j];
        cs[18] = ca;   // chunk total of a
    }
}

// ---------------------------------------------------------------------------
// Scan phase B: per (b,h): sequential exclusive scan over 16 chunk summaries.
// Chunk c's state in global-lg terms = (m - prefA, d, n).
// ---------------------------------------------------------------------------
__global__ __launch_bounds__(64) void scan_phaseB(const float* __restrict__ chunkSum,
                                                  float* __restrict__ chunkPref) {
    int bh = threadIdx.x;
    if (bh >= 16) return;
    float M = -INFINITY, D = 0.f, N[16];
    #pragma unroll
    for (int j = 0; j < 16; j++) N[j] = 0.f;
    float pA = 0.f;
    for (int c = 0; c < 16; c++) {
        float* out = chunkPref + (size_t)(bh * 16 + c) * 20;
        out[0] = M; out[1] = D;
        #pragma unroll
        for (int j = 0; j < 16; j++) out[2 + j] = N[j];
        out[18] = pA;
        const float* cs = chunkSum + (size_t)(bh * 16 + c) * 20;
        float m = cs[0] - pA, d = cs[1];
        float mn = fmaxf(M, m);
        float al = __expf(M - mn), be = __expf(m - mn);
        D = D * al + d * be;
        #pragma unroll
        for (int j = 0; j < 16; j++) N[j] = N[j] * al + cs[2 + j] * be;
        M = mn;
        pA += cs[18];
    }
}

// ---------------------------------------------------------------------------
// Scan phase C: combine element-local state with chunk-exclusive prefix,
// normalize, gate, write Y in bf16 (input to the output GEMM).
// ---------------------------------------------------------------------------
__global__ __launch_bounds__(128) void scan_phaseC(const float* __restrict__ stateWS,
                                                   const float* __restrict__ chunkPref,
                                                   const ushort_t* __restrict__ C1,
                                                   const float* __restrict__ bg,
                                                   ushort_t* __restrict__ Ybf) {
    const int blk = blockIdx.x;
    const int bh = blk >> 4, chunk = blk & 15;
    const int b = bh >> 2, h = bh & 3;
    const int tid = threadIdx.x;
    const int t = chunk * CHSZ_ + tid;
    const size_t row = (size_t)b * T_ + t;
    const size_t eidx = (size_t)bh * T_ + t;

    const float* cp = chunkPref + (size_t)(bh * 16 + chunk) * 20;
    float M = cp[0], D = cp[1], pA = cp[18];
    float m = stateWS[eidx] - pA;
    float d = stateWS[32768 + eidx];
    float mn = fmaxf(M, m);
    float al = __expf(M - mn), be = __expf(m - mn);
    float den = D * al + d * be;
    float invd = 1.f / den;

    const ushort_t* gp = C1 + row * 256 + 192 + h * 16;
    u16x8 g0 = *(const u16x8*)gp;
    u16x8 g1 = *(const u16x8*)(gp + 8);
    u16x8 o0, o1;
    #pragma unroll
    for (int j = 0; j < 16; j++) {
        float Nj = cp[2 + j] * al + stateWS[(size_t)(2 + j) * 32768 + eidx] * be;
        float gpre = ((j < 8) ? bf2f(g0[j]) : bf2f(g1[j - 8])) + bg[h * 16 + j];
        float gate = 1.f / (1.f + __expf(-gpre));
        ushort_t yb = f2bf(Nj * invd * gate);
        if (j < 8) o0[j] = yb; else o1[j - 8] = yb;
    }
    *(u16x8*)(Ybf + row * 64 + h * 16) = o0;
    *(u16x8*)(Ybf + row * 64 + h * 16 + 8) = o1;
}

// ---------------------------------------------------------------------------
extern "C" void kernel_launch(void* const* d_in, const int* in_sizes, int n_in,
                              void* d_out, int out_size, void* d_ws, size_t ws_size,
                              hipStream_t stream) {
    const float* x  = (const float*)d_in[0];
    const float* Wq = (const float*)d_in[1];
    const float* Wk = (const float*)d_in[2];
    const float* Wv = (const float*)d_in[3];
    const float* Wa = (const float*)d_in[4];
    const float* ba = (const float*)d_in[5];
    const float* Wg = (const float*)d_in[6];
    const float* bg = (const float*)d_in[7];
    const float* Wo = (const float*)d_in[8];
    float* out = (float*)d_out;

    char* w = (char*)d_ws;
    ushort_t* WcatT    = (ushort_t*)w;  w += 256 * 512 * 2;        // 262144
    ushort_t* WoT      = (ushort_t*)w;  w += 512 * 64 * 2;         // 65536
    float*    Aarr     = (float*)w;     w += (size_t)ROWS_ * 4 * 4;// 131072
    ushort_t* C1       = (ushort_t*)w;  w += (size_t)ROWS_ * 256 * 2; // 4 MiB
    float*    stateWS  = (float*)w;     w += (size_t)18 * 32768 * 4;  // 2.25 MiB
    float*    chunkSum = (float*)w;     w += 256 * 20 * 4;
    float*    chunkPref= (float*)w;     w += 256 * 20 * 4;
    ushort_t* Ybf      = (ushort_t*)w;  w += (size_t)ROWS_ * 64 * 2;  // 1 MiB
    // total ~8.1 MB (< the 11.1 MB used successfully last round)

    a_proj<<<128, 256, 0, stream>>>(x, Wa, ba, Aarr);
    pack_w_bf<<<640, 256, 0, stream>>>(Wq, Wk, Wv, Wg, Wo, WcatT, WoT);

    // projections: C1(8192x256, bf16) = x @ [Wq|Wk|Wv|Wg]
    gemm_bt<float, ushort_t><<<dim3(2, 128), 256, 0, stream>>>(x, WcatT, C1, ROWS_, 256, D_);

    scan_phaseA<<<256, 128, 0, stream>>>(C1, Aarr, stateWS, chunkSum);
    scan_phaseB<<<1, 64, 0, stream>>>(chunkSum, chunkPref);
    scan_phaseC<<<256, 128, 0, stream>>>(stateWS, chunkPref, C1, bg, Ybf);

    // out(8192x512, fp32) = Y @ Wo
    gemm_bt<ushort_t, float><<<dim3(4, 128), 256, 0, stream>>>(Ybf, WoT, out, ROWS_, D_, 64);
}

// Round 3
// 128.243 us; speedup vs baseline: 1.4962x; 1.1994x over previous
//
#include <hip/hip_runtime.h>
#include <math.h>

// Problem constants
#define B_    4
#define T_    2048
#define D_    512
#define H_    4
#define ROWS_ 8192
#define CHSZ_ 128     // timesteps per chunk; 16 chunks per (b,h)

typedef unsigned short ushort_t;
typedef unsigned int   uint_t;
typedef __attribute__((ext_vector_type(8))) __bf16         bfx8;
typedef __attribute__((ext_vector_type(8))) unsigned short u16x8;
typedef __attribute__((ext_vector_type(4))) float          fx4;

__device__ __forceinline__ ushort_t f2bf(float f) {
    union { float f; uint_t u; } v; v.f = f;
    return (ushort_t)((v.u + 0x7FFFu + ((v.u >> 16) & 1u)) >> 16);
}
__device__ __forceinline__ float bf2f(ushort_t u) {
    union { uint_t u; float f; } v; v.u = ((uint_t)u) << 16; return v.f;
}

// ---------------------------------------------------------------------------
// prep: one wave per row. x(row) -> xbf(row) [bf16], and
// Aarr[row][h] = -softplus(x·Wa[:,h] + ba[h])  (fp32-exact decay path).
// ---------------------------------------------------------------------------
__global__ __launch_bounds__(256) void prep(const float* __restrict__ x,
                                            const float* __restrict__ Wa,
                                            const float* __restrict__ ba,
                                            ushort_t* __restrict__ xbf,
                                            float* __restrict__ Aarr) {
    const int wave = threadIdx.x >> 6, lane = threadIdx.x & 63;
    const int row = blockIdx.x * 4 + wave;
    const float* xp = x + (size_t)row * D_ + lane * 8;
    float4 f0 = *(const float4*)xp;
    float4 f1 = *(const float4*)(xp + 4);
    float xv[8] = {f0.x, f0.y, f0.z, f0.w, f1.x, f1.y, f1.z, f1.w};

    u16x8 u;
    #pragma unroll
    for (int j = 0; j < 8; j++) u[j] = f2bf(xv[j]);
    *(u16x8*)(xbf + (size_t)row * D_ + lane * 8) = u;

    float a0 = 0.f, a1 = 0.f, a2 = 0.f, a3 = 0.f;
    #pragma unroll
    for (int j = 0; j < 8; j++) {
        float4 w = *(const float4*)&Wa[(size_t)(lane * 8 + j) * 4];
        a0 = fmaf(xv[j], w.x, a0);
        a1 = fmaf(xv[j], w.y, a1);
        a2 = fmaf(xv[j], w.z, a2);
        a3 = fmaf(xv[j], w.w, a3);
    }
    #pragma unroll
    for (int off = 32; off; off >>= 1) {
        a0 += __shfl_xor(a0, off);
        a1 += __shfl_xor(a1, off);
        a2 += __shfl_xor(a2, off);
        a3 += __shfl_xor(a3, off);
    }
    if (lane == 0) {
        float z[4] = {a0 + ba[0], a1 + ba[1], a2 + ba[2], a3 + ba[3]};
        float r[4];
        #pragma unroll
        for (int h = 0; h < 4; h++)
            r[h] = -(fmaxf(z[h], 0.f) + log1pf(expf(-fabsf(z[h]))));
        *(float4*)&Aarr[(size_t)row * 4] = make_float4(r[0], r[1], r[2], r[3]);
    }
}

// ---------------------------------------------------------------------------
// pack: WcatT2 (256 x 512 bf16, HEAD-MAJOR rows: h*64 + {q16|k16|v16|g16})
//       WoT    (512 x 64 bf16, transposed Wo)
// ---------------------------------------------------------------------------
__global__ __launch_bounds__(256) void pack_w(const float* __restrict__ Wq,
                                              const float* __restrict__ Wk,
                                              const float* __restrict__ Wv,
                                              const float* __restrict__ Wg,
                                              const float* __restrict__ Wo,
                                              ushort_t* __restrict__ WcatT2,
                                              ushort_t* __restrict__ WoT) {
    int idx = blockIdx.x * 256 + threadIdx.x;
    if (idx < 256 * 512) {
        int n = idx >> 9, d = idx & 511;
        int h = n >> 6, r = n & 63, part = r >> 4, j = r & 15;
        int col = h * 16 + j;
        const float* W = (part == 0) ? Wq : (part == 1) ? Wk : (part == 2) ? Wv : Wg;
        WcatT2[idx] = f2bf(W[(size_t)d * 64 + col]);
    } else {
        int r = idx - 256 * 512;          // 0..32767 = n*64 + k
        int n = r >> 6, k = r & 63;
        WoT[r] = f2bf(Wo[(size_t)k * 512 + n]);
    }
}

// ---------------------------------------------------------------------------
// gemm_scanA: fused projection GEMM (128x64 tile, K=512) + chunk-local scan.
// Grid: 256 blocks = 64 row-chunks x 4 heads, head-major (same-chunk heads
// share an XCD for xbf L2 reuse). Block tile: rows rc*128.., cols = head h's
// q|k|v|g (WcatT2 rows h*64..h*64+64). After the GEMM the C-tile is written
// to LDS (bf16, reusing As) and 128 threads run:
//   bid = q·k/4 ; cumA block-scan (a from Aarr, fp32-exact) ; lg = bid - cumA
//   inclusive softmax-state scan (m,d,n[16]) over the 128-step chunk.
// Outputs: per-element states (18 planes), per-chunk summary, g-tile (bf16).
// ---------------------------------------------------------------------------
__global__ __launch_bounds__(256) void gemm_scanA(const ushort_t* __restrict__ xbf,
                                                  const ushort_t* __restrict__ WcatT2,
                                                  const float* __restrict__ Aarr,
                                                  float* __restrict__ stateWS,
                                                  float* __restrict__ chunkSum,
                                                  ushort_t* __restrict__ gBuf) {
    __shared__ ushort_t As[128 * 72];   // reused as Ct after K-loop
    __shared__ ushort_t Bs[64 * 72];
    __shared__ float s_a0;
    __shared__ float s_state[18];

    const int rc = blockIdx.x & 63;     // row chunk (b*16 + chunk)
    const int h  = blockIdx.x >> 6;
    const int m0 = rc * 128;            // global row base
    const int n0 = h * 64;              // WcatT2 row base
    const int b  = rc >> 4, chunk = rc & 15;
    const int bh = b * 4 + h;

    const int tid = threadIdx.x;
    const int wave = tid >> 6, lane = tid & 63;
    const int fr = lane & 15, quad = lane >> 4;
    const int sr = tid >> 3, sc = (tid & 7) * 8;

    fx4 acc[2][4];
    #pragma unroll
    for (int i = 0; i < 2; i++)
        #pragma unroll
        for (int j = 0; j < 4; j++) acc[i][j] = (fx4)0.f;

    for (int k0 = 0; k0 < D_; k0 += 64) {
        #pragma unroll
        for (int s = 0; s < 4; s++) {
            int r = s * 32 + sr;
            *(u16x8*)&As[r * 72 + sc] = *(const u16x8*)(xbf + (size_t)(m0 + r) * D_ + k0 + sc);
        }
        #pragma unroll
        for (int s = 0; s < 2; s++) {
            int r = s * 32 + sr;
            *(u16x8*)&Bs[r * 72 + sc] = *(const u16x8*)(WcatT2 + (size_t)(n0 + r) * D_ + k0 + sc);
        }
        __syncthreads();
        #pragma unroll
        for (int ks = 0; ks < 64; ks += 32) {
            bfx8 af[2], bfr[4];
            #pragma unroll
            for (int mi = 0; mi < 2; mi++)
                af[mi] = *(const bfx8*)&As[(wave * 32 + mi * 16 + fr) * 72 + ks + quad * 8];
            #pragma unroll
            for (int ni = 0; ni < 4; ni++)
                bfr[ni] = *(const bfx8*)&Bs[(ni * 16 + fr) * 72 + ks + quad * 8];
            #pragma unroll
            for (int mi = 0; mi < 2; mi++)
                #pragma unroll
                for (int ni = 0; ni < 4; ni++)
                    acc[mi][ni] = __builtin_amdgcn_mfma_f32_16x16x32_bf16(af[mi], bfr[ni], acc[mi][ni], 0, 0, 0);
        }
        __syncthreads();
    }

    // C-tile (bf16) into As-as-Ct: row_local x 72 stride, cols 0..63
    #pragma unroll
    for (int mi = 0; mi < 2; mi++)
        #pragma unroll
        for (int ni = 0; ni < 4; ni++)
            #pragma unroll
            for (int r = 0; r < 4; r++) {
                int rl = wave * 32 + mi * 16 + quad * 4 + r;
                int cl = ni * 16 + fr;
                As[rl * 72 + cl] = f2bf(acc[mi][ni][r]);
            }
    __syncthreads();

    // ---- chunk-local scan: 128 active threads (one per row) ----
    const bool active = (tid < 128);
    float bid = 0.f, a = 0.f;
    float n[16];
    if (active) {
        const ushort_t* ct = &As[tid * 72];
        u16x8 q0 = *(const u16x8*)(ct +  0), q1 = *(const u16x8*)(ct +  8);
        u16x8 k0 = *(const u16x8*)(ct + 16), k1 = *(const u16x8*)(ct + 24);
        u16x8 v0 = *(const u16x8*)(ct + 32), v1 = *(const u16x8*)(ct + 40);
        #pragma unroll
        for (int j = 0; j < 8; j++) {
            bid = fmaf(bf2f(q0[j]), bf2f(k0[j]), bid);
            bid = fmaf(bf2f(q1[j]), bf2f(k1[j]), bid);
            n[j]     = bf2f(v0[j]);
            n[8 + j] = bf2f(v1[j]);
        }
        bid *= 0.25f;
        a = Aarr[(size_t)(m0 + tid) * 4 + h];
    } else {
        #pragma unroll
        for (int j = 0; j < 16; j++) n[j] = 0.f;
    }

    // cumA: inclusive scan over 128 rows (2 waves + LDS bridge)
    float ca = a;
    #pragma unroll
    for (int off = 1; off < 64; off <<= 1) {
        float up = __shfl_up(ca, off);
        if (lane >= off) ca += up;
    }
    if (tid == 63) s_a0 = ca;
    __syncthreads();
    if (active && wave == 1) ca += s_a0;

    float lg = bid - ca;
    float m = lg, d = 1.f;

    // inclusive softmax-state scan within wave
    #pragma unroll
    for (int off = 1; off < 64; off <<= 1) {
        float Lm = __shfl_up(m, off);
        float Ld = __shfl_up(d, off);
        float Ln[16];
        #pragma unroll
        for (int j = 0; j < 16; j++) Ln[j] = __shfl_up(n[j], off);
        if (lane >= off) {
            float mn = fmaxf(Lm, m);
            float al = __expf(Lm - mn), be = __expf(m - mn);
            d = Ld * al + d * be;
            #pragma unroll
            for (int j = 0; j < 16; j++) n[j] = Ln[j] * al + n[j] * be;
            m = mn;
        }
    }
    if (tid == 63) {
        s_state[0] = m; s_state[1] = d;
        #pragma unroll
        for (int j = 0; j < 16; j++) s_state[2 + j] = n[j];
    }
    __syncthreads();
    if (active && wave == 1) {
        float Lm = s_state[0], Ld = s_state[1];
        float mn = fmaxf(Lm, m);
        float al = __expf(Lm - mn), be = __expf(m - mn);
        d = Ld * al + d * be;
        #pragma unroll
        for (int j = 0; j < 16; j++) n[j] = s_state[2 + j] * al + n[j] * be;
        m = mn;
    }

    if (active) {
        const int t = chunk * CHSZ_ + tid;
        const size_t eidx = (size_t)bh * T_ + t;
        stateWS[eidx] = m;
        stateWS[32768 + eidx] = d;
        #pragma unroll
        for (int j = 0; j < 16; j++) stateWS[(size_t)(2 + j) * 32768 + eidx] = n[j];

        // g-tile out (cols 48..63 of Ct)
        const ushort_t* ct = &As[tid * 72];
        u16x8 g0 = *(const u16x8*)(ct + 48), g1 = *(const u16x8*)(ct + 56);
        *(u16x8*)(gBuf + eidx * 16)     = g0;
        *(u16x8*)(gBuf + eidx * 16 + 8) = g1;

        if (tid == 127) {
            float* cs = chunkSum + (size_t)(bh * 16 + chunk) * 20;
            cs[0] = m; cs[1] = d;
            #pragma unroll
            for (int j = 0; j < 16; j++) cs[2 + j] = n[j];
            cs[18] = ca;
        }
    }
}

// ---------------------------------------------------------------------------
// scanBC: per (bh,chunk) block. Thread 0 recomputes the chunk-exclusive
// prefix state sequentially from chunkSum (<=15 combines, L2-served), then
// all 128 threads combine, normalize, gate, write Ybf.
// ---------------------------------------------------------------------------
__global__ __launch_bounds__(128) void scanBC(const float* __restrict__ stateWS,
                                              const float* __restrict__ chunkSum,
                                              const ushort_t* __restrict__ gBuf,
                                              const float* __restrict__ bg,
                                              ushort_t* __restrict__ Ybf) {
    __shared__ float sp[20];
    const int blk = blockIdx.x;
    const int bh = blk >> 4, chunk = blk & 15;
    const int b = bh >> 2, h = bh & 3;
    const int tid = threadIdx.x;

    if (tid == 0) {
        float M = -INFINITY, D = 0.f, N[16];
        #pragma unroll
        for (int j = 0; j < 16; j++) N[j] = 0.f;
        float pA = 0.f;
        for (int c = 0; c < chunk; c++) {
            const float* cs = chunkSum + (size_t)(bh * 16 + c) * 20;
            float m = cs[0] - pA, d = cs[1];
            float mn = fmaxf(M, m);
            float al = __expf(M - mn), be = __expf(m - mn);
            D = D * al + d * be;
            #pragma unroll
            for (int j = 0; j < 16; j++) N[j] = N[j] * al + cs[2 + j] * be;
            M = mn;
            pA += cs[18];
        }
        sp[0] = M; sp[1] = D;
        #pragma unroll
        for (int j = 0; j < 16; j++) sp[2 + j] = N[j];
        sp[18] = pA;
    }
    __syncthreads();

    const int t = chunk * CHSZ_ + tid;
    const size_t eidx = (size_t)bh * T_ + t;
    float M = sp[0], D = sp[1], pA = sp[18];
    float m = stateWS[eidx] - pA;
    float d = stateWS[32768 + eidx];
    float mn = fmaxf(M, m);
    float al = __expf(M - mn), be = __expf(m - mn);
    float invd = 1.f / (D * al + d * be);

    u16x8 g0 = *(const u16x8*)(gBuf + eidx * 16);
    u16x8 g1 = *(const u16x8*)(gBuf + eidx * 16 + 8);
    u16x8 o0, o1;
    #pragma unroll
    for (int j = 0; j < 16; j++) {
        float Nj = sp[2 + j] * al + stateWS[(size_t)(2 + j) * 32768 + eidx] * be;
        float gpre = ((j < 8) ? bf2f(g0[j]) : bf2f(g1[j - 8])) + bg[h * 16 + j];
        float gate = 1.f / (1.f + __expf(-gpre));
        ushort_t yb = f2bf(Nj * invd * gate);
        if (j < 8) o0[j] = yb; else o1[j - 8] = yb;
    }
    const size_t row = (size_t)b * T_ + t;
    *(u16x8*)(Ybf + row * 64 + h * 16)     = o0;
    *(u16x8*)(Ybf + row * 64 + h * 16 + 8) = o1;
}

// ---------------------------------------------------------------------------
// Output GEMM (proven round-2 code): C(MxN) = A(MxK) @ BT(NxK)^T, bf16 MFMA.
// BM=64 BN=128 BK=64; A bf16, C fp32.
// ---------------------------------------------------------------------------
__global__ __launch_bounds__(256) void gemm_bt(const ushort_t* __restrict__ A,
                                               const ushort_t* __restrict__ BT,
                                               float* __restrict__ C,
                                               int M, int N, int K) {
    __shared__ ushort_t As[64 * 72];
    __shared__ ushort_t Bs[128 * 72];
    const int tid = threadIdx.x;
    const int wave = tid >> 6, lane = tid & 63;
    const int m0 = blockIdx.y * 64, n0 = blockIdx.x * 128;
    const int wr = wave >> 1, wc = wave & 1;

    fx4 acc[2][4];
    #pragma unroll
    for (int i = 0; i < 2; i++)
        #pragma unroll
        for (int j = 0; j < 4; j++) acc[i][j] = (fx4)0.f;

    const int sr = tid >> 3, sc = (tid & 7) * 8;

    for (int k0 = 0; k0 < K; k0 += 64) {
        #pragma unroll
        for (int s = 0; s < 2; s++) {
            int r = s * 32 + sr;
            *(u16x8*)&As[r * 72 + sc] = *(const u16x8*)(A + (size_t)(m0 + r) * K + k0 + sc);
        }
        #pragma unroll
        for (int s = 0; s < 4; s++) {
            int r = s * 32 + sr;
            *(u16x8*)&Bs[r * 72 + sc] = *(const u16x8*)(BT + (size_t)(n0 + r) * K + k0 + sc);
        }
        __syncthreads();
        const int fr = lane & 15, quad = lane >> 4;
        #pragma unroll
        for (int ks = 0; ks < 64; ks += 32) {
            bfx8 af[2], bfr[4];
            #pragma unroll
            for (int mi = 0; mi < 2; mi++)
                af[mi] = *(const bfx8*)&As[(wr * 32 + mi * 16 + fr) * 72 + ks + quad * 8];
            #pragma unroll
            for (int ni = 0; ni < 4; ni++)
                bfr[ni] = *(const bfx8*)&Bs[(wc * 64 + ni * 16 + fr) * 72 + ks + quad * 8];
            #pragma unroll
            for (int mi = 0; mi < 2; mi++)
                #pragma unroll
                for (int ni = 0; ni < 4; ni++)
                    acc[mi][ni] = __builtin_amdgcn_mfma_f32_16x16x32_bf16(af[mi], bfr[ni], acc[mi][ni], 0, 0, 0);
        }
        __syncthreads();
    }

    const int fr = lane & 15, quad = lane >> 4;
    #pragma unroll
    for (int mi = 0; mi < 2; mi++)
        #pragma unroll
        for (int ni = 0; ni < 4; ni++)
            #pragma unroll
            for (int r = 0; r < 4; r++) {
                int rr = m0 + wr * 32 + mi * 16 + quad * 4 + r;
                int cc = n0 + wc * 64 + ni * 16 + fr;
                C[(size_t)rr * N + cc] = acc[mi][ni][r];
            }
}

// ---------------------------------------------------------------------------
extern "C" void kernel_launch(void* const* d_in, const int* in_sizes, int n_in,
                              void* d_out, int out_size, void* d_ws, size_t ws_size,
                              hipStream_t stream) {
    const float* x  = (const float*)d_in[0];
    const float* Wq = (const float*)d_in[1];
    const float* Wk = (const float*)d_in[2];
    const float* Wv = (const float*)d_in[3];
    const float* Wa = (const float*)d_in[4];
    const float* ba = (const float*)d_in[5];
    const float* Wg = (const float*)d_in[6];
    const float* bg = (const float*)d_in[7];
    const float* Wo = (const float*)d_in[8];
    float* out = (float*)d_out;

    char* w = (char*)d_ws;
    ushort_t* xbf      = (ushort_t*)w;  w += (size_t)ROWS_ * D_ * 2;     // 8 MiB
    ushort_t* WcatT2   = (ushort_t*)w;  w += 256 * 512 * 2;              // 256 KiB
    ushort_t* WoT      = (ushort_t*)w;  w += 512 * 64 * 2;               // 64 KiB
    float*    Aarr     = (float*)w;     w += (size_t)ROWS_ * 4 * 4;      // 128 KiB
    float*    stateWS  = (float*)w;     w += (size_t)18 * 32768 * 4;     // 2.25 MiB
    float*    chunkSum = (float*)w;     w += 256 * 20 * 4;               // 20 KiB
    ushort_t* gBuf     = (ushort_t*)w;  w += (size_t)32768 * 16 * 2;     // 1 MiB
    ushort_t* Ybf      = (ushort_t*)w;  w += (size_t)ROWS_ * 64 * 2;     // 1 MiB

    prep<<<2048, 256, 0, stream>>>(x, Wa, ba, xbf, Aarr);
    pack_w<<<640, 256, 0, stream>>>(Wq, Wk, Wv, Wg, Wo, WcatT2, WoT);
    gemm_scanA<<<256, 256, 0, stream>>>(xbf, WcatT2, Aarr, stateWS, chunkSum, gBuf);
    scanBC<<<256, 128, 0, stream>>>(stateWS, chunkSum, gBuf, bg, Ybf);
    gemm_bt<<<dim3(4, 128), 256, 0, stream>>>(Ybf, WoT, out, ROWS_, D_, 64);
}